// Round 6
// baseline (139.075 us; speedup 1.0000x reference)
//
#include <hip/hip_runtime.h>

#define NHEAD  4
#define D_OUT  128
#define HDIM   512   // NHEAD * D_OUT
#define NEG    0.2f

typedef __attribute__((ext_vector_type(8))) short short8;
typedef __attribute__((ext_vector_type(4))) float f32x4;

// pack two fp32 -> bf16x2 (round-to-nearest-even)
__device__ __forceinline__ unsigned pack_bf16(float a, float b) {
    unsigned ua = __float_as_uint(a);
    unsigned ub = __float_as_uint(b);
    ua = (ua + 0x7fffu + ((ua >> 16) & 1u)) >> 16;
    ub = (ub + 0x7fffu + ((ub >> 16) & 1u)) >> 16;
    return ua | (ub << 16);
}
__device__ __forceinline__ float bf_lo(unsigned u) { return __uint_as_float(u << 16); }
__device__ __forceinline__ float bf_hi(unsigned u) { return __uint_as_float(u & 0xffff0000u); }

// ---------------------------------------------------------------------------
// convert W (128 x 512 fp32) -> Wt (512 x 128 bf16), transposed for MFMA B-op
// ---------------------------------------------------------------------------
__global__ __launch_bounds__(256) void convert_w(const float* __restrict__ W,
                                                 ushort* __restrict__ Wt) {
    int t = blockIdx.x * 256 + threadIdx.x;    // 4096 threads: 128 c4 x 32 kq
    int c = (t >> 5) * 4;
    int k = (t & 31) * 4;
    float4 r0 = *(const float4*)(W + (size_t)(k + 0) * HDIM + c);
    float4 r1 = *(const float4*)(W + (size_t)(k + 1) * HDIM + c);
    float4 r2 = *(const float4*)(W + (size_t)(k + 2) * HDIM + c);
    float4 r3 = *(const float4*)(W + (size_t)(k + 3) * HDIM + c);
    const float* f0 = (const float*)&r0;
    const float* f1 = (const float*)&r1;
    const float* f2 = (const float*)&r2;
    const float* f3 = (const float*)&r3;
#pragma unroll
    for (int j = 0; j < 4; ++j) {
        uint2 u;
        u.x = pack_bf16(f0[j], f1[j]);
        u.y = pack_bf16(f2[j], f3[j]);
        *(uint2*)(Wt + (size_t)(c + j) * 128 + k) = u;
    }
}

// ---------------------------------------------------------------------------
// gemm_h: block = 64 rows x ALL 4 heads (x staged once -> 10 MB not 40 MB).
// Per head: re-stage Bt (32 KB, Wt is L2-resident), MFMA 16x16x32 bf16 with
// swapped operands (lane holds 4 consecutive cols), fused a_src/a_dst dots.
// LDS: As 16 KB + Bt 32 KB = 48 KB -> 3 blocks/CU.
// ---------------------------------------------------------------------------
__global__ __launch_bounds__(256) void gemm_h(const float* __restrict__ x,
                                              const ushort* __restrict__ Wt,
                                              const float* __restrict__ att_src,
                                              const float* __restrict__ att_dst,
                                              unsigned* __restrict__ hb,
                                              float* __restrict__ a_src,
                                              float* __restrict__ a_dst, int M) {
    __shared__ ushort As[64 * 128];    // [row][k] bf16, idx ^= ((row&7)<<3)
    __shared__ ushort Bt[128 * 128];   // [col][k] bf16, idx ^= ((col&7)<<3)
    const int tid  = threadIdx.x;
    const int row0 = blockIdx.x * 64;

    // stage A: 64 rows x 128 k = 1024 granules of 8 bf16, coalesced fp32 reads
#pragma unroll
    for (int it = 0; it < 4; ++it) {
        int flat = tid + it * 256;
        int r = flat >> 4, g = flat & 15;
        int grow = row0 + r; if (grow >= M) grow = M - 1;
        const float* px = x + (size_t)grow * 128 + g * 8;
        float4 a = *(const float4*)px;
        float4 b = *(const float4*)(px + 4);
        uint4 u;
        u.x = pack_bf16(a.x, a.y); u.y = pack_bf16(a.z, a.w);
        u.z = pack_bf16(b.x, b.y); u.w = pack_bf16(b.z, b.w);
        int us = r * 128 + ((g * 8) ^ ((r & 7) << 3));
        *(uint4*)(&As[us]) = u;
    }
    __syncthreads();

    const int w  = tid >> 6;      // wave: rows w*16 .. w*16+15
    const int l  = tid & 63;
    const int lr = l & 15;
    const int lk = l >> 4;
    const int row  = w * 16 + lr;
    const int grow = row0 + row;

    // A-fragments depend only on kg: load once, reuse for all 4 heads
    short8 af[4];
#pragma unroll
    for (int kg = 0; kg < 4; ++kg) {
        int us = row * 128 + ((kg * 32 + lk * 8) ^ ((row & 7) << 3));
        af[kg] = *(const short8*)(&As[us]);
    }

    for (int head = 0; head < NHEAD; ++head) {
        // stage Bt for this head: 128 cols x 128 k = 2048 granules
#pragma unroll
        for (int it = 0; it < 8; ++it) {
            int flat = tid + it * 256;
            int c = flat >> 4, g = flat & 15;
            uint4 u = *(const uint4*)(Wt + (size_t)(head * 128 + c) * 128 + g * 8);
            int us = c * 128 + ((g * 8) ^ ((c & 7) << 3));
            *(uint4*)(&Bt[us]) = u;
        }
        __syncthreads();

        f32x4 acc[8];
#pragma unroll
        for (int cr = 0; cr < 8; ++cr) acc[cr] = (f32x4){0.f, 0.f, 0.f, 0.f};

#pragma unroll
        for (int kg = 0; kg < 4; ++kg) {
#pragma unroll
            for (int cr = 0; cr < 8; ++cr) {
                int col = cr * 16 + lr;
                int us = col * 128 + ((kg * 32 + lk * 8) ^ ((col & 7) << 3));
                short8 bf = *(const short8*)(&Bt[us]);
                acc[cr] = __builtin_amdgcn_mfma_f32_16x16x32_bf16(
                    bf, af[kg], acc[cr], 0, 0, 0);
            }
        }

        // epilogue: lane holds row `grow`, cols (cr*16 + lk*4 + j) of head
        uint2 u8[8];
        float ps = 0.f, pd = 0.f;
#pragma unroll
        for (int cr = 0; cr < 8; ++cr) {
            float4 avs = *(const float4*)(att_src + head * 128 + cr * 16 + lk * 4);
            float4 avd = *(const float4*)(att_dst + head * 128 + cr * 16 + lk * 4);
            f32x4 c4 = acc[cr];
            u8[cr].x = pack_bf16(c4[0], c4[1]);
            u8[cr].y = pack_bf16(c4[2], c4[3]);
            ps += c4[0] * avs.x + c4[1] * avs.y + c4[2] * avs.z + c4[3] * avs.w;
            pd += c4[0] * avd.x + c4[1] * avd.y + c4[2] * avd.z + c4[3] * avd.w;
        }
        ps += __shfl_xor(ps, 16); ps += __shfl_xor(ps, 32);
        pd += __shfl_xor(pd, 16); pd += __shfl_xor(pd, 32);
        if (grow < M) {
#pragma unroll
            for (int cr = 0; cr < 8; ++cr)
                *(uint2*)(hb + (size_t)grow * 256 + head * 64 + cr * 8 + lk * 2) = u8[cr];
            if (lk == 0) {
                a_src[grow * NHEAD + head] = ps;
                a_dst[grow * NHEAD + head] = pd;
            }
        }
        __syncthreads();   // Bt reads done before next head overwrites
    }
}

// ---------------------------------------------------------------------------
// CSR build (self-loops appended). edge_index arrives as int32.
// ---------------------------------------------------------------------------
__global__ void count_deg(const int* __restrict__ ei, int E, int Nn,
                          int* __restrict__ deg) {
    int i = blockIdx.x * blockDim.x + threadIdx.x;
    if (i >= E + Nn) return;
    int dst = (i < E) ? ei[E + i] : (i - E);
    atomicAdd(&deg[dst], 1);
}

// chunked scan: 1024 threads x 32 elems = up to 32768 (N = 20000 fits)
__global__ __launch_bounds__(1024) void scan_offsets(const int* __restrict__ deg,
                                                     int* __restrict__ offs, int n) {
    const int C = 32;
    int t = threadIdx.x;
    int base = t * C;
    int local[C];
    int sum = 0;
#pragma unroll
    for (int j = 0; j < C; ++j) {
        int i = base + j;
        int v = (i < n) ? deg[i] : 0;
        sum += v;
        local[j] = sum;
    }
    int lane = t & 63, wave = t >> 6;
    int v = sum;
#pragma unroll
    for (int off = 1; off < 64; off <<= 1) {
        int u = __shfl_up(v, off);
        if (lane >= off) v += u;
    }
    __shared__ int wsum[16];
    __shared__ int wpre[16];
    if (lane == 63) wsum[wave] = v;
    __syncthreads();
    if (t < 16) {
        int wv = wsum[t];
#pragma unroll
        for (int off = 1; off < 16; off <<= 1) {
            int u = __shfl_up(wv, off, 16);
            if (t >= off) wv += u;
        }
        wpre[t] = wv;
    }
    __syncthreads();
    int excl_in_wave = v - sum;
    int wbase = (wave > 0) ? wpre[wave - 1] : 0;
    int tbase = wbase + excl_in_wave;
#pragma unroll
    for (int j = 0; j < C; ++j) {
        int i = base + j;
        if (i < n) offs[i + 1] = tbase + local[j];
    }
    if (t == 0) offs[0] = 0;
}

// fill CSR only (attention weights now computed inline in aggregate)
__global__ void fill_csr(const int* __restrict__ ei, int E, int Nn,
                         const int* __restrict__ offs, int* __restrict__ fill,
                         int* __restrict__ csr) {
    int i = blockIdx.x * blockDim.x + threadIdx.x;
    if (i >= E + Nn) return;
    int src, dst;
    if (i < E) { src = ei[i]; dst = ei[E + i]; }
    else       { src = dst = i - E; }
    int pos = offs[dst] + atomicAdd(&fill[dst], 1);
    csr[pos] = src;
}

// ---------------------------------------------------------------------------
// aggregate: one WAVE per node (4/block), 4-wide unrolled edge loop ->
// 4 independent 1 KB gathers in flight. w = exp(leaky(a_src[s]+a_dst[n]))
// computed inline (a_src is 320 KB, L2-resident). Head-mean via shfl_xor.
// lane l: head l>>4, bf16 dims 8l..8l+7.
// ---------------------------------------------------------------------------
__global__ __launch_bounds__(256) void aggregate(const uint4* __restrict__ hb4,
                                                 const int* __restrict__ offs,
                                                 const int* __restrict__ csr,
                                                 const float* __restrict__ a_src,
                                                 const float* __restrict__ a_dst,
                                                 const float* __restrict__ bias,
                                                 float* __restrict__ out, int Nn) {
    int n = blockIdx.x * 4 + (threadIdx.x >> 6);
    if (n >= Nn) return;
    int l  = threadIdx.x & 63;
    int hd = l >> 4;
    int beg = offs[n], end = offs[n + 1];
    float ad = a_dst[n * NHEAD + hd];

    float a0 = 0.f, a1 = 0.f, a2 = 0.f, a3 = 0.f;
    float a4 = 0.f, a5 = 0.f, a6 = 0.f, a7 = 0.f;
    float den = 0.f;

    int e = beg;
    for (; e + 3 < end; e += 4) {
        int s0 = csr[e], s1 = csr[e + 1], s2 = csr[e + 2], s3 = csr[e + 3];
        float x0 = a_src[s0 * NHEAD + hd];
        float x1 = a_src[s1 * NHEAD + hd];
        float x2 = a_src[s2 * NHEAD + hd];
        float x3 = a_src[s3 * NHEAD + hd];
        uint4 v0 = hb4[(size_t)s0 * 64 + l];
        uint4 v1 = hb4[(size_t)s1 * 64 + l];
        uint4 v2 = hb4[(size_t)s2 * 64 + l];
        uint4 v3 = hb4[(size_t)s3 * 64 + l];
        float t;
        t = x0 + ad; t = (t >= 0.f) ? t : NEG * t; float w0 = __expf(t);
        t = x1 + ad; t = (t >= 0.f) ? t : NEG * t; float w1 = __expf(t);
        t = x2 + ad; t = (t >= 0.f) ? t : NEG * t; float w2 = __expf(t);
        t = x3 + ad; t = (t >= 0.f) ? t : NEG * t; float w3 = __expf(t);
        den += (w0 + w1) + (w2 + w3);
        a0 += w0 * bf_lo(v0.x) + w1 * bf_lo(v1.x) + w2 * bf_lo(v2.x) + w3 * bf_lo(v3.x);
        a1 += w0 * bf_hi(v0.x) + w1 * bf_hi(v1.x) + w2 * bf_hi(v2.x) + w3 * bf_hi(v3.x);
        a2 += w0 * bf_lo(v0.y) + w1 * bf_lo(v1.y) + w2 * bf_lo(v2.y) + w3 * bf_lo(v3.y);
        a3 += w0 * bf_hi(v0.y) + w1 * bf_hi(v1.y) + w2 * bf_hi(v2.y) + w3 * bf_hi(v3.y);
        a4 += w0 * bf_lo(v0.z) + w1 * bf_lo(v1.z) + w2 * bf_lo(v2.z) + w3 * bf_lo(v3.z);
        a5 += w0 * bf_hi(v0.z) + w1 * bf_hi(v1.z) + w2 * bf_hi(v2.z) + w3 * bf_hi(v3.z);
        a6 += w0 * bf_lo(v0.w) + w1 * bf_lo(v1.w) + w2 * bf_lo(v2.w) + w3 * bf_lo(v3.w);
        a7 += w0 * bf_hi(v0.w) + w1 * bf_hi(v1.w) + w2 * bf_hi(v2.w) + w3 * bf_hi(v3.w);
    }
    for (; e < end; ++e) {
        int s0 = csr[e];
        float x0 = a_src[s0 * NHEAD + hd];
        uint4 v0 = hb4[(size_t)s0 * 64 + l];
        float t = x0 + ad; t = (t >= 0.f) ? t : NEG * t;
        float w0 = __expf(t);
        den += w0;
        a0 += w0 * bf_lo(v0.x); a1 += w0 * bf_hi(v0.x);
        a2 += w0 * bf_lo(v0.y); a3 += w0 * bf_hi(v0.y);
        a4 += w0 * bf_lo(v0.z); a5 += w0 * bf_hi(v0.z);
        a6 += w0 * bf_lo(v0.w); a7 += w0 * bf_hi(v0.w);
    }

    float inv = 1.0f / den;
    a0 *= inv; a1 *= inv; a2 *= inv; a3 *= inv;
    a4 *= inv; a5 *= inv; a6 *= inv; a7 *= inv;
    // sum across the 4 heads (lanes l, l^16, l^32, l^48)
    a0 += __shfl_xor(a0, 16); a0 += __shfl_xor(a0, 32);
    a1 += __shfl_xor(a1, 16); a1 += __shfl_xor(a1, 32);
    a2 += __shfl_xor(a2, 16); a2 += __shfl_xor(a2, 32);
    a3 += __shfl_xor(a3, 16); a3 += __shfl_xor(a3, 32);
    a4 += __shfl_xor(a4, 16); a4 += __shfl_xor(a4, 32);
    a5 += __shfl_xor(a5, 16); a5 += __shfl_xor(a5, 32);
    a6 += __shfl_xor(a6, 16); a6 += __shfl_xor(a6, 32);
    a7 += __shfl_xor(a7, 16); a7 += __shfl_xor(a7, 32);
    if (l < 16) {
        float4 b0 = *(const float4*)(bias + l * 8);
        float4 b1 = *(const float4*)(bias + l * 8 + 4);
        float4 o0, o1;
        o0.x = fmaxf(a0 * 0.25f + b0.x, 0.f);
        o0.y = fmaxf(a1 * 0.25f + b0.y, 0.f);
        o0.z = fmaxf(a2 * 0.25f + b0.z, 0.f);
        o0.w = fmaxf(a3 * 0.25f + b0.w, 0.f);
        o1.x = fmaxf(a4 * 0.25f + b1.x, 0.f);
        o1.y = fmaxf(a5 * 0.25f + b1.y, 0.f);
        o1.z = fmaxf(a6 * 0.25f + b1.z, 0.f);
        o1.w = fmaxf(a7 * 0.25f + b1.w, 0.f);
        *(float4*)(out + (size_t)n * D_OUT + l * 8)     = o0;
        *(float4*)(out + (size_t)n * D_OUT + l * 8 + 4) = o1;
    }
}

// ---------------------------------------------------------------------------
extern "C" void kernel_launch(void* const* d_in, const int* in_sizes, int n_in,
                              void* d_out, int out_size, void* d_ws, size_t ws_size,
                              hipStream_t stream) {
    const float* x       = (const float*)d_in[0];
    const float* W       = (const float*)d_in[1];
    const float* att_src = (const float*)d_in[2];
    const float* att_dst = (const float*)d_in[3];
    const float* bias    = (const float*)d_in[4];
    const int*   ei      = (const int*)d_in[5];
    float*       out     = (float*)d_out;

    const int N    = in_sizes[0] / 128;
    const int E    = in_sizes[5] / 2;
    const int Etot = E + N;

    char* ws = (char*)d_ws;
    size_t off = 0;
    auto alloc = [&](size_t bytes) -> char* {
        char* p = ws + off;
        off += (bytes + 255) & ~(size_t)255;
        return p;
    };
    unsigned* hb    = (unsigned*)alloc((size_t)N * 256 * sizeof(unsigned)); // h bf16x2
    ushort*   Wt    = (ushort*)alloc((size_t)HDIM * 128 * sizeof(ushort));  // W^T bf16
    float*    a_src = (float*)alloc((size_t)N * NHEAD * sizeof(float));
    float*    a_dst = (float*)alloc((size_t)N * NHEAD * sizeof(float));
    int*      deg   = (int*)alloc((size_t)N * sizeof(int));
    int*      fillc = (int*)alloc((size_t)N * sizeof(int));
    size_t    zspan = (size_t)((char*)(fillc + N) - (char*)deg);
    int*      offs  = (int*)alloc((size_t)(N + 1) * sizeof(int));
    int*      csr   = (int*)alloc((size_t)Etot * sizeof(int));

    hipMemsetAsync(deg, 0, zspan, stream);

    convert_w<<<16, 256, 0, stream>>>(W, Wt);
    gemm_h<<<(N + 63) / 64, 256, 0, stream>>>(x, Wt, att_src, att_dst, hb,
                                              a_src, a_dst, N);
    count_deg<<<(Etot + 255) / 256, 256, 0, stream>>>(ei, E, N, deg);
    scan_offsets<<<1, 1024, 0, stream>>>(deg, offs, N);
    fill_csr<<<(Etot + 255) / 256, 256, 0, stream>>>(ei, E, N, offs, fillc, csr);
    aggregate<<<(N + 3) / 4, 256, 0, stream>>>((const uint4*)hb, offs, csr,
                                               a_src, a_dst, bias, out, N);
}

// Round 7
// 131.920 us; speedup vs baseline: 1.0542x; 1.0542x over previous
//
#include <hip/hip_runtime.h>

#define NHEAD  4
#define D_OUT  128
#define HDIM   512   // NHEAD * D_OUT
#define NEG    0.2f

typedef __attribute__((ext_vector_type(8))) short short8;
typedef __attribute__((ext_vector_type(4))) float f32x4;

// pack two fp32 -> bf16x2 (round-to-nearest-even)
__device__ __forceinline__ unsigned pack_bf16(float a, float b) {
    unsigned ua = __float_as_uint(a);
    unsigned ub = __float_as_uint(b);
    ua = (ua + 0x7fffu + ((ua >> 16) & 1u)) >> 16;
    ub = (ub + 0x7fffu + ((ub >> 16) & 1u)) >> 16;
    return ua | (ub << 16);
}
__device__ __forceinline__ float bf_lo(unsigned u) { return __uint_as_float(u << 16); }
__device__ __forceinline__ float bf_hi(unsigned u) { return __uint_as_float(u & 0xffff0000u); }

// ---------------------------------------------------------------------------
// prep: one kernel does (a) x -> xb bf16, (b) W -> Wt bf16 transposed,
// (c) deg count. Flat-index partitioned; each segment coalesced.
// ---------------------------------------------------------------------------
__global__ __launch_bounds__(256) void prep(const float* __restrict__ x,
                                            const float* __restrict__ W,
                                            const int* __restrict__ ei,
                                            uint4* __restrict__ xb4,
                                            ushort* __restrict__ Wt,
                                            int* __restrict__ deg,
                                            int M, int E, int Nn) {
    const int JX = M * 16;          // x granules: 16 x uint4 (8 bf16) per row
    const int JW = 4096;            // W tiles
    int t = blockIdx.x * 256 + threadIdx.x;
    if (t < JX) {
        int row = t >> 4, g = t & 15;
        const float* px = x + (size_t)row * 128 + g * 8;
        float4 a = *(const float4*)px;
        float4 b = *(const float4*)(px + 4);
        uint4 u;
        u.x = pack_bf16(a.x, a.y); u.y = pack_bf16(a.z, a.w);
        u.z = pack_bf16(b.x, b.y); u.w = pack_bf16(b.z, b.w);
        xb4[t] = u;
    } else if (t < JX + JW) {
        int t2 = t - JX;
        int c = (t2 >> 5) * 4;
        int k = (t2 & 31) * 4;
        float4 r0 = *(const float4*)(W + (size_t)(k + 0) * HDIM + c);
        float4 r1 = *(const float4*)(W + (size_t)(k + 1) * HDIM + c);
        float4 r2 = *(const float4*)(W + (size_t)(k + 2) * HDIM + c);
        float4 r3 = *(const float4*)(W + (size_t)(k + 3) * HDIM + c);
        const float* f0 = (const float*)&r0;
        const float* f1 = (const float*)&r1;
        const float* f2 = (const float*)&r2;
        const float* f3 = (const float*)&r3;
#pragma unroll
        for (int j = 0; j < 4; ++j) {
            uint2 u;
            u.x = pack_bf16(f0[j], f1[j]);
            u.y = pack_bf16(f2[j], f3[j]);
            *(uint2*)(Wt + (size_t)(c + j) * 128 + k) = u;
        }
    } else {
        int i = t - JX - JW;
        if (i < E + Nn) {
            int dst = (i < E) ? ei[E + i] : (i - E);
            atomicAdd(&deg[dst], 1);
        }
    }
}

// ---------------------------------------------------------------------------
// gemm_h: h[M][512] = xb[M][128] @ W, bf16 MFMA 16x16x32. Block = 128 rows x
// one head (grid 157x4). Swapped operands -> lane holds 4 consecutive cols.
// Fused a_src/a_dst head-dots, no atomics. LDS 64 KB (2 blocks/CU).
// ---------------------------------------------------------------------------
__global__ __launch_bounds__(256) void gemm_h(const uint4* __restrict__ xb4,
                                              const ushort* __restrict__ Wt,
                                              const float* __restrict__ att_src,
                                              const float* __restrict__ att_dst,
                                              unsigned* __restrict__ hb,
                                              float* __restrict__ a_src,
                                              float* __restrict__ a_dst, int M) {
    __shared__ ushort As[128 * 128];   // [row][k] bf16, idx ^= ((row&7)<<3)
    __shared__ ushort Bt[128 * 128];   // [col][k] bf16, idx ^= ((col&7)<<3)
    const int tid  = threadIdx.x;
    const int row0 = blockIdx.x * 128;
    const int head = blockIdx.y;
    const int col0 = head * 128;

    // stage A: 128 rows x 16 granules (uint4 = 8 bf16), coalesced
#pragma unroll
    for (int it = 0; it < 8; ++it) {
        int flat = tid + it * 256;
        int r = flat >> 4, g = flat & 15;
        int grow = row0 + r; if (grow >= M) grow = M - 1;
        uint4 u = xb4[(size_t)grow * 16 + g];
        int us = r * 128 + ((g * 8) ^ ((r & 7) << 3));
        *(uint4*)(&As[us]) = u;
    }
    // stage B: Wt bf16, straight copy with swizzle
#pragma unroll
    for (int it = 0; it < 8; ++it) {
        int flat = tid + it * 256;
        int c = flat >> 4, g = flat & 15;
        uint4 u = *(const uint4*)(Wt + (size_t)(col0 + c) * 128 + g * 8);
        int us = c * 128 + ((g * 8) ^ ((c & 7) << 3));
        *(uint4*)(&Bt[us]) = u;
    }
    __syncthreads();

    const int w  = tid >> 6;      // wave: rows w*32 .. +31
    const int l  = tid & 63;
    const int lr = l & 15;
    const int lk = l >> 4;

    f32x4 acc[8][2];              // [cr][rr]
#pragma unroll
    for (int cr = 0; cr < 8; ++cr)
#pragma unroll
        for (int rr = 0; rr < 2; ++rr) acc[cr][rr] = (f32x4){0.f, 0.f, 0.f, 0.f};

#pragma unroll
    for (int kg = 0; kg < 4; ++kg) {
        short8 af[2];
#pragma unroll
        for (int rr = 0; rr < 2; ++rr) {
            int row = w * 32 + rr * 16 + lr;
            int us = row * 128 + ((kg * 32 + lk * 8) ^ ((row & 7) << 3));
            af[rr] = *(const short8*)(&As[us]);
        }
#pragma unroll
        for (int cr = 0; cr < 8; ++cr) {
            int col = cr * 16 + lr;
            int us = col * 128 + ((kg * 32 + lk * 8) ^ ((col & 7) << 3));
            short8 bf = *(const short8*)(&Bt[us]);
#pragma unroll
            for (int rr = 0; rr < 2; ++rr)
                acc[cr][rr] = __builtin_amdgcn_mfma_f32_16x16x32_bf16(
                    bf, af[rr], acc[cr][rr], 0, 0, 0);
        }
    }

    // epilogue: lane holds rows (w*32+rr*16+lr), cols (cr*16+lk*4+j)
    float4 avs[8], avd[8];
#pragma unroll
    for (int cr = 0; cr < 8; ++cr) {
        avs[cr] = *(const float4*)(att_src + col0 + cr * 16 + lk * 4);
        avd[cr] = *(const float4*)(att_dst + col0 + cr * 16 + lk * 4);
    }
#pragma unroll
    for (int rr = 0; rr < 2; ++rr) {
        uint2 u8[8];
        float ps = 0.f, pd = 0.f;
#pragma unroll
        for (int cr = 0; cr < 8; ++cr) {
            f32x4 c4 = acc[cr][rr];
            u8[cr].x = pack_bf16(c4[0], c4[1]);
            u8[cr].y = pack_bf16(c4[2], c4[3]);
            ps += c4[0] * avs[cr].x + c4[1] * avs[cr].y + c4[2] * avs[cr].z + c4[3] * avs[cr].w;
            pd += c4[0] * avd[cr].x + c4[1] * avd[cr].y + c4[2] * avd[cr].z + c4[3] * avd[cr].w;
        }
        ps += __shfl_xor(ps, 16); ps += __shfl_xor(ps, 32);
        pd += __shfl_xor(pd, 16); pd += __shfl_xor(pd, 32);
        int row = row0 + w * 32 + rr * 16 + lr;
        if (row < M) {
#pragma unroll
            for (int cr = 0; cr < 8; ++cr)
                *(uint2*)(hb + (size_t)row * 256 + head * 64 + cr * 8 + lk * 2) = u8[cr];
            if (lk == 0) {
                a_src[row * NHEAD + head] = ps;
                a_dst[row * NHEAD + head] = pd;
            }
        }
    }
}

// ---------------------------------------------------------------------------
// chunked scan: 1024 threads x 32 elems = up to 32768 (N = 20000 fits)
// ---------------------------------------------------------------------------
__global__ __launch_bounds__(1024) void scan_offsets(const int* __restrict__ deg,
                                                     int* __restrict__ offs, int n) {
    const int C = 32;
    int t = threadIdx.x;
    int base = t * C;
    int local[C];
    int sum = 0;
#pragma unroll
    for (int j = 0; j < C; ++j) {
        int i = base + j;
        int v = (i < n) ? deg[i] : 0;
        sum += v;
        local[j] = sum;
    }
    int lane = t & 63, wave = t >> 6;
    int v = sum;
#pragma unroll
    for (int off = 1; off < 64; off <<= 1) {
        int u = __shfl_up(v, off);
        if (lane >= off) v += u;
    }
    __shared__ int wsum[16];
    __shared__ int wpre[16];
    if (lane == 63) wsum[wave] = v;
    __syncthreads();
    if (t < 16) {
        int wv = wsum[t];
#pragma unroll
        for (int off = 1; off < 16; off <<= 1) {
            int u = __shfl_up(wv, off, 16);
            if (t >= off) wv += u;
        }
        wpre[t] = wv;
    }
    __syncthreads();
    int excl_in_wave = v - sum;
    int wbase = (wave > 0) ? wpre[wave - 1] : 0;
    int tbase = wbase + excl_in_wave;
#pragma unroll
    for (int j = 0; j < C; ++j) {
        int i = base + j;
        if (i < n) offs[i + 1] = tbase + local[j];
    }
    if (t == 0) offs[0] = 0;
}

// fill CSR (self-loops appended)
__global__ void fill_csr(const int* __restrict__ ei, int E, int Nn,
                         const int* __restrict__ offs, int* __restrict__ fill,
                         int* __restrict__ csr) {
    int i = blockIdx.x * blockDim.x + threadIdx.x;
    if (i >= E + Nn) return;
    int src, dst;
    if (i < E) { src = ei[i]; dst = ei[E + i]; }
    else       { src = dst = i - E; }
    int pos = offs[dst] + atomicAdd(&fill[dst], 1);
    csr[pos] = src;
}

// ---------------------------------------------------------------------------
// aggregate: TWO waves per node (dim-split), 2 nodes per 256-thr block.
// wave w2 of node n handles bf16 dims [w2*256, w2*256+256): lane l gathers
// uint2 (4 bf16) at granule w2*64+l; head = w2*2 + (l>>5). 4-wide unrolled
// edge loop; weights inline from L2-resident a_src. Head-mean: shfl_xor(32)
// for the in-wave head pair, 1 KB LDS for the cross-wave pair.
// ---------------------------------------------------------------------------
__global__ __launch_bounds__(256) void aggregate(const uint2* __restrict__ hb2,
                                                 const int* __restrict__ offs,
                                                 const int* __restrict__ csr,
                                                 const float* __restrict__ a_src,
                                                 const float* __restrict__ a_dst,
                                                 const float* __restrict__ bias,
                                                 float* __restrict__ out, int Nn) {
    __shared__ float red[2][128];
    const int half = threadIdx.x >> 6;   // 0..3
    const int slot = half >> 1;          // node within block
    const int w2   = half & 1;           // dim-half
    const int n    = blockIdx.x * 2 + slot;
    const int l    = threadIdx.x & 63;
    const bool valid = (n < Nn);

    float c0 = 0.f, c1 = 0.f, c2 = 0.f, c3 = 0.f, den = 0.f;
    if (valid) {
        const int head = w2 * 2 + (l >> 5);
        const float ad = a_dst[n * NHEAD + head];
        const int beg = offs[n], end = offs[n + 1];
        const size_t lofs = (size_t)w2 * 64 + l;
        int e = beg;
        for (; e + 3 < end; e += 4) {
            int s0 = csr[e], s1 = csr[e + 1], s2 = csr[e + 2], s3 = csr[e + 3];
            float x0 = a_src[s0 * NHEAD + head];
            float x1 = a_src[s1 * NHEAD + head];
            float x2 = a_src[s2 * NHEAD + head];
            float x3 = a_src[s3 * NHEAD + head];
            uint2 v0 = hb2[(size_t)s0 * 128 + lofs];
            uint2 v1 = hb2[(size_t)s1 * 128 + lofs];
            uint2 v2 = hb2[(size_t)s2 * 128 + lofs];
            uint2 v3 = hb2[(size_t)s3 * 128 + lofs];
            float t;
            t = x0 + ad; t = (t >= 0.f) ? t : NEG * t; float w0 = __expf(t);
            t = x1 + ad; t = (t >= 0.f) ? t : NEG * t; float w1 = __expf(t);
            t = x2 + ad; t = (t >= 0.f) ? t : NEG * t; float w2f = __expf(t);
            t = x3 + ad; t = (t >= 0.f) ? t : NEG * t; float w3 = __expf(t);
            den += (w0 + w1) + (w2f + w3);
            c0 += w0 * bf_lo(v0.x) + w1 * bf_lo(v1.x) + w2f * bf_lo(v2.x) + w3 * bf_lo(v3.x);
            c1 += w0 * bf_hi(v0.x) + w1 * bf_hi(v1.x) + w2f * bf_hi(v2.x) + w3 * bf_hi(v3.x);
            c2 += w0 * bf_lo(v0.y) + w1 * bf_lo(v1.y) + w2f * bf_lo(v2.y) + w3 * bf_lo(v3.y);
            c3 += w0 * bf_hi(v0.y) + w1 * bf_hi(v1.y) + w2f * bf_hi(v2.y) + w3 * bf_hi(v3.y);
        }
        for (; e < end; ++e) {
            int s0 = csr[e];
            float x0 = a_src[s0 * NHEAD + head];
            uint2 v0 = hb2[(size_t)s0 * 128 + lofs];
            float t = x0 + ad; t = (t >= 0.f) ? t : NEG * t;
            float w0 = __expf(t);
            den += w0;
            c0 += w0 * bf_lo(v0.x); c1 += w0 * bf_hi(v0.x);
            c2 += w0 * bf_lo(v0.y); c3 += w0 * bf_hi(v0.y);
        }
        float inv = 1.0f / den;
        c0 *= inv; c1 *= inv; c2 *= inv; c3 *= inv;
    }
    // in-wave head pair: lanes l and l^32 hold the same output dim
    c0 += __shfl_xor(c0, 32);
    c1 += __shfl_xor(c1, 32);
    c2 += __shfl_xor(c2, 32);
    c3 += __shfl_xor(c3, 32);
    if (valid && w2 == 1 && l < 32) {
        red[slot][4 * l + 0] = c0;
        red[slot][4 * l + 1] = c1;
        red[slot][4 * l + 2] = c2;
        red[slot][4 * l + 3] = c3;
    }
    __syncthreads();
    if (valid && w2 == 0 && l < 32) {
        float4 b = *(const float4*)(bias + 4 * l);
        float4 o;
        o.x = fmaxf((c0 + red[slot][4 * l + 0]) * 0.25f + b.x, 0.f);
        o.y = fmaxf((c1 + red[slot][4 * l + 1]) * 0.25f + b.y, 0.f);
        o.z = fmaxf((c2 + red[slot][4 * l + 2]) * 0.25f + b.z, 0.f);
        o.w = fmaxf((c3 + red[slot][4 * l + 3]) * 0.25f + b.w, 0.f);
        *(float4*)(out + (size_t)n * D_OUT + 4 * l) = o;
    }
}

// ---------------------------------------------------------------------------
extern "C" void kernel_launch(void* const* d_in, const int* in_sizes, int n_in,
                              void* d_out, int out_size, void* d_ws, size_t ws_size,
                              hipStream_t stream) {
    const float* x       = (const float*)d_in[0];
    const float* W       = (const float*)d_in[1];
    const float* att_src = (const float*)d_in[2];
    const float* att_dst = (const float*)d_in[3];
    const float* bias    = (const float*)d_in[4];
    const int*   ei      = (const int*)d_in[5];
    float*       out     = (float*)d_out;

    const int N    = in_sizes[0] / 128;
    const int E    = in_sizes[5] / 2;
    const int Etot = E + N;

    char* ws = (char*)d_ws;
    size_t off = 0;
    auto alloc = [&](size_t bytes) -> char* {
        char* p = ws + off;
        off += (bytes + 255) & ~(size_t)255;
        return p;
    };
    unsigned* hb    = (unsigned*)alloc((size_t)N * 256 * sizeof(unsigned)); // h bf16x2
    uint4*    xb4   = (uint4*)alloc((size_t)N * 16 * sizeof(uint4));        // x bf16
    ushort*   Wt    = (ushort*)alloc((size_t)HDIM * 128 * sizeof(ushort));  // W^T bf16
    float*    a_src = (float*)alloc((size_t)N * NHEAD * sizeof(float));
    float*    a_dst = (float*)alloc((size_t)N * NHEAD * sizeof(float));
    int*      deg   = (int*)alloc((size_t)N * sizeof(int));
    int*      fillc = (int*)alloc((size_t)N * sizeof(int));
    size_t    zspan = (size_t)((char*)(fillc + N) - (char*)deg);
    int*      offs  = (int*)alloc((size_t)(N + 1) * sizeof(int));
    int*      csr   = (int*)alloc((size_t)Etot * sizeof(int));

    hipMemsetAsync(deg, 0, zspan, stream);

    const int jobs = N * 16 + 4096 + Etot;
    prep<<<(jobs + 255) / 256, 256, 0, stream>>>(x, W, ei, xb4, Wt, deg, N, E, N);
    dim3 ggrid((N + 127) / 128, NHEAD);
    gemm_h<<<ggrid, 256, 0, stream>>>(xb4, Wt, att_src, att_dst, hb, a_src, a_dst, N);
    scan_offsets<<<1, 1024, 0, stream>>>(deg, offs, N);
    fill_csr<<<(Etot + 255) / 256, 256, 0, stream>>>(ei, E, N, offs, fillc, csr);
    aggregate<<<(N + 1) / 2, 256, 0, stream>>>((const uint2*)hb, offs, csr,
                                               a_src, a_dst, bias, out, N);
}

// Round 8
// 126.528 us; speedup vs baseline: 1.0992x; 1.0426x over previous
//
#include <hip/hip_runtime.h>

#define NHEAD  4
#define D_OUT  128
#define HDIM   512   // NHEAD * D_OUT
#define NEG    0.2f

typedef __attribute__((ext_vector_type(8))) short short8;
typedef __attribute__((ext_vector_type(4))) float f32x4;

// pack two fp32 -> bf16x2 (round-to-nearest-even)
__device__ __forceinline__ unsigned pack_bf16(float a, float b) {
    unsigned ua = __float_as_uint(a);
    unsigned ub = __float_as_uint(b);
    ua = (ua + 0x7fffu + ((ua >> 16) & 1u)) >> 16;
    ub = (ub + 0x7fffu + ((ub >> 16) & 1u)) >> 16;
    return ua | (ub << 16);
}
__device__ __forceinline__ float bf_lo(unsigned u) { return __uint_as_float(u << 16); }
__device__ __forceinline__ float bf_hi(unsigned u) { return __uint_as_float(u & 0xffff0000u); }

// ---------------------------------------------------------------------------
// prep: (a) x -> xb bf16, (b) W -> Wt bf16 transposed, (c) deg count.
// ---------------------------------------------------------------------------
__global__ __launch_bounds__(256) void prep(const float* __restrict__ x,
                                            const float* __restrict__ W,
                                            const int* __restrict__ ei,
                                            uint4* __restrict__ xb4,
                                            ushort* __restrict__ Wt,
                                            int* __restrict__ deg,
                                            int M, int E, int Nn) {
    const int JX = M * 16;          // x granules: 16 x uint4 (8 bf16) per row
    const int JW = 4096;            // W tiles
    int t = blockIdx.x * 256 + threadIdx.x;
    if (t < JX) {
        int row = t >> 4, g = t & 15;
        const float* px = x + (size_t)row * 128 + g * 8;
        float4 a = *(const float4*)px;
        float4 b = *(const float4*)(px + 4);
        uint4 u;
        u.x = pack_bf16(a.x, a.y); u.y = pack_bf16(a.z, a.w);
        u.z = pack_bf16(b.x, b.y); u.w = pack_bf16(b.z, b.w);
        xb4[t] = u;
    } else if (t < JX + JW) {
        int t2 = t - JX;
        int c = (t2 >> 5) * 4;
        int k = (t2 & 31) * 4;
        float4 r0 = *(const float4*)(W + (size_t)(k + 0) * HDIM + c);
        float4 r1 = *(const float4*)(W + (size_t)(k + 1) * HDIM + c);
        float4 r2 = *(const float4*)(W + (size_t)(k + 2) * HDIM + c);
        float4 r3 = *(const float4*)(W + (size_t)(k + 3) * HDIM + c);
        const float* f0 = (const float*)&r0;
        const float* f1 = (const float*)&r1;
        const float* f2 = (const float*)&r2;
        const float* f3 = (const float*)&r3;
#pragma unroll
        for (int j = 0; j < 4; ++j) {
            uint2 u;
            u.x = pack_bf16(f0[j], f1[j]);
            u.y = pack_bf16(f2[j], f3[j]);
            *(uint2*)(Wt + (size_t)(c + j) * 128 + k) = u;
        }
    } else {
        int i = t - JX - JW;
        if (i < E + Nn) {
            int dst = (i < E) ? ei[E + i] : (i - E);
            atomicAdd(&deg[dst], 1);
        }
    }
}

// ---------------------------------------------------------------------------
// gemm_h: h[M][512] = xb[M][128] @ W, bf16 MFMA 16x16x32. Block = 128 rows x
// one head (grid 157x4). Swapped operands -> lane holds 4 consecutive cols.
// Epilogue: pack acc into LDS tile (stride-68 u32, bank-safe) then store
// COALESCED (16 thr x uint4 per row) -- kills the 8B-scatter write-allocate.
// Fused a_src/a_dst head-dots, no atomics.
// ---------------------------------------------------------------------------
__global__ __launch_bounds__(256) void gemm_h(const uint4* __restrict__ xb4,
                                              const ushort* __restrict__ Wt,
                                              const float* __restrict__ att_src,
                                              const float* __restrict__ att_dst,
                                              unsigned* __restrict__ hb,
                                              float* __restrict__ a_src,
                                              float* __restrict__ a_dst, int M) {
    __shared__ ushort As[128 * 136];   // 34.8 KB: A-tile (first 32 KB) / out staging
    __shared__ ushort Bt[128 * 128];   // [col][k] bf16, idx ^= ((col&7)<<3)
    const int tid  = threadIdx.x;
    const int row0 = blockIdx.x * 128;
    const int head = blockIdx.y;
    const int col0 = head * 128;

    // stage A: 128 rows x 16 granules (uint4 = 8 bf16), coalesced
#pragma unroll
    for (int it = 0; it < 8; ++it) {
        int flat = tid + it * 256;
        int r = flat >> 4, g = flat & 15;
        int grow = row0 + r; if (grow >= M) grow = M - 1;
        uint4 u = xb4[(size_t)grow * 16 + g];
        int us = r * 128 + ((g * 8) ^ ((r & 7) << 3));
        *(uint4*)(&As[us]) = u;
    }
    // stage B: Wt bf16, straight copy with swizzle
#pragma unroll
    for (int it = 0; it < 8; ++it) {
        int flat = tid + it * 256;
        int c = flat >> 4, g = flat & 15;
        uint4 u = *(const uint4*)(Wt + (size_t)(col0 + c) * 128 + g * 8);
        int us = c * 128 + ((g * 8) ^ ((c & 7) << 3));
        *(uint4*)(&Bt[us]) = u;
    }
    __syncthreads();

    const int w  = tid >> 6;      // wave: rows w*32 .. +31
    const int l  = tid & 63;
    const int lr = l & 15;
    const int lk = l >> 4;

    // preload ALL A-fragments (As region reusable afterwards)
    short8 af[2][4];
#pragma unroll
    for (int rr = 0; rr < 2; ++rr)
#pragma unroll
        for (int kg = 0; kg < 4; ++kg) {
            int row = w * 32 + rr * 16 + lr;
            int us = row * 128 + ((kg * 32 + lk * 8) ^ ((row & 7) << 3));
            af[rr][kg] = *(const short8*)(&As[us]);
        }

    f32x4 acc[8][2];              // [cr][rr]
#pragma unroll
    for (int cr = 0; cr < 8; ++cr)
#pragma unroll
        for (int rr = 0; rr < 2; ++rr) acc[cr][rr] = (f32x4){0.f, 0.f, 0.f, 0.f};

#pragma unroll
    for (int kg = 0; kg < 4; ++kg) {
#pragma unroll
        for (int cr = 0; cr < 8; ++cr) {
            int col = cr * 16 + lr;
            int us = col * 128 + ((kg * 32 + lk * 8) ^ ((col & 7) << 3));
            short8 bf = *(const short8*)(&Bt[us]);
#pragma unroll
            for (int rr = 0; rr < 2; ++rr)
                acc[cr][rr] = __builtin_amdgcn_mfma_f32_16x16x32_bf16(
                    bf, af[rr][kg], acc[cr][rr], 0, 0, 0);
        }
    }

    // attention head-dots + bf16 pack
    float4 avs[8], avd[8];
#pragma unroll
    for (int cr = 0; cr < 8; ++cr) {
        avs[cr] = *(const float4*)(att_src + col0 + cr * 16 + lk * 4);
        avd[cr] = *(const float4*)(att_dst + col0 + cr * 16 + lk * 4);
    }
    uint2 u8[8][2];
    float ps[2], pd[2];
#pragma unroll
    for (int rr = 0; rr < 2; ++rr) {
        ps[rr] = 0.f; pd[rr] = 0.f;
#pragma unroll
        for (int cr = 0; cr < 8; ++cr) {
            f32x4 c4 = acc[cr][rr];
            u8[cr][rr].x = pack_bf16(c4[0], c4[1]);
            u8[cr][rr].y = pack_bf16(c4[2], c4[3]);
            ps[rr] += c4[0] * avs[cr].x + c4[1] * avs[cr].y + c4[2] * avs[cr].z + c4[3] * avs[cr].w;
            pd[rr] += c4[0] * avd[cr].x + c4[1] * avd[cr].y + c4[2] * avd[cr].z + c4[3] * avd[cr].w;
        }
        ps[rr] += __shfl_xor(ps[rr], 16); ps[rr] += __shfl_xor(ps[rr], 32);
        pd[rr] += __shfl_xor(pd[rr], 16); pd[rr] += __shfl_xor(pd[rr], 32);
    }

    __syncthreads();   // all waves done reading As -> safe to reuse as staging

    // write acc tile into staging: stag[row][c] u32, stride 68 (bank-safe, 16B-aligned)
    unsigned* stag = (unsigned*)As;
#pragma unroll
    for (int rr = 0; rr < 2; ++rr) {
        int row = w * 32 + rr * 16 + lr;
#pragma unroll
        for (int cr = 0; cr < 8; ++cr)
            *(uint2*)(&stag[row * 68 + cr * 8 + lk * 2]) = u8[cr][rr];
        int grow = row0 + row;
        if (lk == 0 && grow < M) {
            a_src[grow * NHEAD + head] = ps[rr];
            a_dst[grow * NHEAD + head] = pd[rr];
        }
    }
    __syncthreads();

    // coalesced store: 128 rows x 16 uint4 (256B/row contiguous)
#pragma unroll
    for (int it = 0; it < 8; ++it) {
        int flat = tid + it * 256;
        int r = flat >> 4, g = flat & 15;
        int grow = row0 + r;
        if (grow < M) {
            uint4 u = *(const uint4*)(&stag[r * 68 + g * 4]);
            *(uint4*)(hb + (size_t)grow * 256 + head * 64 + g * 4) = u;
        }
    }
}

// ---------------------------------------------------------------------------
// chunked scan: 1024 threads x 32 elems = up to 32768 (N = 20000 fits)
// ---------------------------------------------------------------------------
__global__ __launch_bounds__(1024) void scan_offsets(const int* __restrict__ deg,
                                                     int* __restrict__ offs, int n) {
    const int C = 32;
    int t = threadIdx.x;
    int base = t * C;
    int local[C];
    int sum = 0;
#pragma unroll
    for (int j = 0; j < C; ++j) {
        int i = base + j;
        int v = (i < n) ? deg[i] : 0;
        sum += v;
        local[j] = sum;
    }
    int lane = t & 63, wave = t >> 6;
    int v = sum;
#pragma unroll
    for (int off = 1; off < 64; off <<= 1) {
        int u = __shfl_up(v, off);
        if (lane >= off) v += u;
    }
    __shared__ int wsum[16];
    __shared__ int wpre[16];
    if (lane == 63) wsum[wave] = v;
    __syncthreads();
    if (t < 16) {
        int wv = wsum[t];
#pragma unroll
        for (int off = 1; off < 16; off <<= 1) {
            int u = __shfl_up(wv, off, 16);
            if (t >= off) wv += u;
        }
        wpre[t] = wv;
    }
    __syncthreads();
    int excl_in_wave = v - sum;
    int wbase = (wave > 0) ? wpre[wave - 1] : 0;
    int tbase = wbase + excl_in_wave;
#pragma unroll
    for (int j = 0; j < C; ++j) {
        int i = base + j;
        if (i < n) offs[i + 1] = tbase + local[j];
    }
    if (t == 0) offs[0] = 0;
}

// fill CSR (self-loops appended)
__global__ void fill_csr(const int* __restrict__ ei, int E, int Nn,
                         const int* __restrict__ offs, int* __restrict__ fill,
                         int* __restrict__ csr) {
    int i = blockIdx.x * blockDim.x + threadIdx.x;
    if (i >= E + Nn) return;
    int src, dst;
    if (i < E) { src = ei[i]; dst = ei[E + i]; }
    else       { src = dst = i - E; }
    int pos = offs[dst] + atomicAdd(&fill[dst], 1);
    csr[pos] = src;
}

// ---------------------------------------------------------------------------
// aggregate: one WAVE per node (4/block), 4-wide unrolled edge loop ->
// 4 independent 1 KB gathers in flight. w = exp(leaky(a_src[s]+a_dst[n]))
// computed inline (a_src is 320 KB, L2-resident). Head-mean via shfl_xor.
// lane l: head l>>4, bf16 dims 8l..8l+7.
// ---------------------------------------------------------------------------
__global__ __launch_bounds__(256) void aggregate(const uint4* __restrict__ hb4,
                                                 const int* __restrict__ offs,
                                                 const int* __restrict__ csr,
                                                 const float* __restrict__ a_src,
                                                 const float* __restrict__ a_dst,
                                                 const float* __restrict__ bias,
                                                 float* __restrict__ out, int Nn) {
    int n = blockIdx.x * 4 + (threadIdx.x >> 6);
    if (n >= Nn) return;
    int l  = threadIdx.x & 63;
    int hd = l >> 4;
    int beg = offs[n], end = offs[n + 1];
    float ad = a_dst[n * NHEAD + hd];

    float a0 = 0.f, a1 = 0.f, a2 = 0.f, a3 = 0.f;
    float a4 = 0.f, a5 = 0.f, a6 = 0.f, a7 = 0.f;
    float den = 0.f;

    int e = beg;
    for (; e + 3 < end; e += 4) {
        int s0 = csr[e], s1 = csr[e + 1], s2 = csr[e + 2], s3 = csr[e + 3];
        float x0 = a_src[s0 * NHEAD + hd];
        float x1 = a_src[s1 * NHEAD + hd];
        float x2 = a_src[s2 * NHEAD + hd];
        float x3 = a_src[s3 * NHEAD + hd];
        uint4 v0 = hb4[(size_t)s0 * 64 + l];
        uint4 v1 = hb4[(size_t)s1 * 64 + l];
        uint4 v2 = hb4[(size_t)s2 * 64 + l];
        uint4 v3 = hb4[(size_t)s3 * 64 + l];
        float t;
        t = x0 + ad; t = (t >= 0.f) ? t : NEG * t; float w0 = __expf(t);
        t = x1 + ad; t = (t >= 0.f) ? t : NEG * t; float w1 = __expf(t);
        t = x2 + ad; t = (t >= 0.f) ? t : NEG * t; float w2 = __expf(t);
        t = x3 + ad; t = (t >= 0.f) ? t : NEG * t; float w3 = __expf(t);
        den += (w0 + w1) + (w2 + w3);
        a0 += w0 * bf_lo(v0.x) + w1 * bf_lo(v1.x) + w2 * bf_lo(v2.x) + w3 * bf_lo(v3.x);
        a1 += w0 * bf_hi(v0.x) + w1 * bf_hi(v1.x) + w2 * bf_hi(v2.x) + w3 * bf_hi(v3.x);
        a2 += w0 * bf_lo(v0.y) + w1 * bf_lo(v1.y) + w2 * bf_lo(v2.y) + w3 * bf_lo(v3.y);
        a3 += w0 * bf_hi(v0.y) + w1 * bf_hi(v1.y) + w2 * bf_hi(v2.y) + w3 * bf_hi(v3.y);
        a4 += w0 * bf_lo(v0.z) + w1 * bf_lo(v1.z) + w2 * bf_lo(v2.z) + w3 * bf_lo(v3.z);
        a5 += w0 * bf_hi(v0.z) + w1 * bf_hi(v1.z) + w2 * bf_hi(v2.z) + w3 * bf_hi(v3.z);
        a6 += w0 * bf_lo(v0.w) + w1 * bf_lo(v1.w) + w2 * bf_lo(v2.w) + w3 * bf_lo(v3.w);
        a7 += w0 * bf_hi(v0.w) + w1 * bf_hi(v1.w) + w2 * bf_hi(v2.w) + w3 * bf_hi(v3.w);
    }
    for (; e < end; ++e) {
        int s0 = csr[e];
        float x0 = a_src[s0 * NHEAD + hd];
        uint4 v0 = hb4[(size_t)s0 * 64 + l];
        float t = x0 + ad; t = (t >= 0.f) ? t : NEG * t;
        float w0 = __expf(t);
        den += w0;
        a0 += w0 * bf_lo(v0.x); a1 += w0 * bf_hi(v0.x);
        a2 += w0 * bf_lo(v0.y); a3 += w0 * bf_hi(v0.y);
        a4 += w0 * bf_lo(v0.z); a5 += w0 * bf_hi(v0.z);
        a6 += w0 * bf_lo(v0.w); a7 += w0 * bf_hi(v0.w);
    }

    float inv = 1.0f / den;
    a0 *= inv; a1 *= inv; a2 *= inv; a3 *= inv;
    a4 *= inv; a5 *= inv; a6 *= inv; a7 *= inv;
    // sum across the 4 heads (lanes l, l^16, l^32, l^48)
    a0 += __shfl_xor(a0, 16); a0 += __shfl_xor(a0, 32);
    a1 += __shfl_xor(a1, 16); a1 += __shfl_xor(a1, 32);
    a2 += __shfl_xor(a2, 16); a2 += __shfl_xor(a2, 32);
    a3 += __shfl_xor(a3, 16); a3 += __shfl_xor(a3, 32);
    a4 += __shfl_xor(a4, 16); a4 += __shfl_xor(a4, 32);
    a5 += __shfl_xor(a5, 16); a5 += __shfl_xor(a5, 32);
    a6 += __shfl_xor(a6, 16); a6 += __shfl_xor(a6, 32);
    a7 += __shfl_xor(a7, 16); a7 += __shfl_xor(a7, 32);
    if (l < 16) {
        float4 b0 = *(const float4*)(bias + l * 8);
        float4 b1 = *(const float4*)(bias + l * 8 + 4);
        float4 o0, o1;
        o0.x = fmaxf(a0 * 0.25f + b0.x, 0.f);
        o0.y = fmaxf(a1 * 0.25f + b0.y, 0.f);
        o0.z = fmaxf(a2 * 0.25f + b0.z, 0.f);
        o0.w = fmaxf(a3 * 0.25f + b0.w, 0.f);
        o1.x = fmaxf(a4 * 0.25f + b1.x, 0.f);
        o1.y = fmaxf(a5 * 0.25f + b1.y, 0.f);
        o1.z = fmaxf(a6 * 0.25f + b1.z, 0.f);
        o1.w = fmaxf(a7 * 0.25f + b1.w, 0.f);
        *(float4*)(out + (size_t)n * D_OUT + l * 8)     = o0;
        *(float4*)(out + (size_t)n * D_OUT + l * 8 + 4) = o1;
    }
}

// ---------------------------------------------------------------------------
extern "C" void kernel_launch(void* const* d_in, const int* in_sizes, int n_in,
                              void* d_out, int out_size, void* d_ws, size_t ws_size,
                              hipStream_t stream) {
    const float* x       = (const float*)d_in[0];
    const float* W       = (const float*)d_in[1];
    const float* att_src = (const float*)d_in[2];
    const float* att_dst = (const float*)d_in[3];
    const float* bias    = (const float*)d_in[4];
    const int*   ei      = (const int*)d_in[5];
    float*       out     = (float*)d_out;

    const int N    = in_sizes[0] / 128;
    const int E    = in_sizes[5] / 2;
    const int Etot = E + N;

    char* ws = (char*)d_ws;
    size_t off = 0;
    auto alloc = [&](size_t bytes) -> char* {
        char* p = ws + off;
        off += (bytes + 255) & ~(size_t)255;
        return p;
    };
    unsigned* hb    = (unsigned*)alloc((size_t)N * 256 * sizeof(unsigned)); // h bf16x2
    uint4*    xb4   = (uint4*)alloc((size_t)N * 16 * sizeof(uint4));        // x bf16
    ushort*   Wt    = (ushort*)alloc((size_t)HDIM * 128 * sizeof(ushort));  // W^T bf16
    float*    a_src = (float*)alloc((size_t)N * NHEAD * sizeof(float));
    float*    a_dst = (float*)alloc((size_t)N * NHEAD * sizeof(float));
    int*      deg   = (int*)alloc((size_t)N * sizeof(int));
    int*      fillc = (int*)alloc((size_t)N * sizeof(int));
    size_t    zspan = (size_t)((char*)(fillc + N) - (char*)deg);
    int*      offs  = (int*)alloc((size_t)(N + 1) * sizeof(int));
    int*      csr   = (int*)alloc((size_t)Etot * sizeof(int));

    hipMemsetAsync(deg, 0, zspan, stream);

    const int jobs = N * 16 + 4096 + Etot;
    prep<<<(jobs + 255) / 256, 256, 0, stream>>>(x, W, ei, xb4, Wt, deg, N, E, N);
    dim3 ggrid((N + 127) / 128, NHEAD);
    gemm_h<<<ggrid, 256, 0, stream>>>(xb4, Wt, att_src, att_dst, hb, a_src, a_dst, N);
    scan_offsets<<<1, 1024, 0, stream>>>(deg, offs, N);
    fill_csr<<<(Etot + 255) / 256, 256, 0, stream>>>(ei, E, N, offs, fillc, csr);
    aggregate<<<(N + 3) / 4, 256, 0, stream>>>((const uint4*)hb, offs, csr,
                                               a_src, a_dst, bias, out, N);
}